// Round 7
// baseline (225.807 us; speedup 1.0000x reference)
//
#include <hip/hip_runtime.h>

// DCNv1 on MI355X. Deform-GEMM via bf16x3 MFMA (hi/lo split, 3 passes -> ~fp32
// precision). Shapes fixed: B=4, C=64, H=W=128, Cout=64, K=3x3, stride=1, pad=1.

constexpr int B_  = 4;
constexpr int C_  = 64;
constexpr int H_  = 128;
constexpr int W_  = 128;
constexpr int CO_ = 64;
constexpr int K_  = 9;
constexpr int HW_ = H_ * W_;

typedef short bf16x8 __attribute__((ext_vector_type(8)));
typedef float f32x4  __attribute__((ext_vector_type(4)));

#define REP18(M) M(0) M(1) M(2) M(3) M(4) M(5) M(6) M(7) M(8) M(9) M(10) M(11) M(12) M(13) M(14) M(15) M(16) M(17)

// ---------------- workspace layout (float units) ----------------
constexpr size_t XT_OFF   = 0;                                    // NHWC x f32
constexpr size_t OFF_OFF  = XT_OFF + (size_t)B_ * HW_ * C_;       // offsets f32
constexpr size_t WPT2_OFF = OFF_OFF + (size_t)B_ * HW_ * 18;      // w_p^T [c][t][20] f32
constexpr size_t WDH_OFF  = WPT2_OFF + (size_t)C_ * K_ * 20;      // w_d hi bf16 [k][oc][c]
constexpr size_t WDL_OFF  = WDH_OFF + (size_t)K_ * CO_ * C_ / 2;  // w_d lo bf16

__device__ inline short f2bf(float x) {                 // RTN f32->bf16
    unsigned u = __float_as_uint(x);
    return (short)((u + 0x7FFF + ((u >> 16) & 1)) >> 16);
}
__device__ inline float bf2f(short s) {
    return __uint_as_float(((unsigned)(unsigned short)s) << 16);
}

// ---------------- K0a: x NCHW -> NHWC ----------------
__global__ __launch_bounds__(256) void transpose_x_k(const float* __restrict__ x,
                                                     float* __restrict__ xt) {
    __shared__ float tile[64][65];
    int bid = blockIdx.x;           // 1024
    int wt  = bid & 1;
    int h   = (bid >> 1) & 127;
    int b   = bid >> 8;
    int w0  = wt * 64;
    int tid = threadIdx.x;
    int lw = tid & 63, c0 = tid >> 6;
#pragma unroll
    for (int i = 0; i < 16; ++i) {
        int c = c0 * 16 + i;
        tile[c][lw] = x[((b * C_ + c) * H_ + h) * W_ + w0 + lw];
    }
    __syncthreads();
    int lc = tid & 63, wp = tid >> 6;
#pragma unroll
    for (int i = 0; i < 16; ++i) {
        int w = wp * 16 + i;
        xt[((size_t)(b * H_ + h) * W_ + w0 + w) * C_ + lc] = tile[lc][w];
    }
}

// ---------------- K0b: weight prep ----------------
__global__ void transpose_w_k(const float* __restrict__ wd, const float* __restrict__ wp,
                              short* __restrict__ wdh, short* __restrict__ wdl,
                              float* __restrict__ wpt2) {
    int i = blockIdx.x * 256 + threadIdx.x;
    if (i < K_ * CO_ * C_) {               // 36864
        int k  = i / (CO_ * C_);
        int r  = i % (CO_ * C_);
        int oc = r >> 6;
        int c  = r & 63;
        float v = wd[(oc * C_ + c) * K_ + k];
        short h = f2bf(v);
        wdh[i] = h;
        wdl[i] = f2bf(v - bf2f(h));
    }
    if (i < C_ * K_ * 20) {                // 11520
        int j = i % 20;
        int t = (i / 20) % K_;
        int c = i / (20 * K_);
        wpt2[i] = (j < 18) ? wp[((j * C_ + c) * 3 + t / 3) * 3 + (t % 3)] : 0.f;
    }
}

// ---------------- K1: offset conv v5 ----------------
// Block: 64 pix x 4 c-quarters = 256 thr. Grid = B*H*2 = 1024.
// KEY FIX: accumulators are 18 NAMED SCALARS (macro-generated) -> guaranteed
// VGPR residency. Previous acc[18] array lived in scratch (VGPR_Count=24 in
// the profile vs >=36 live values needed) making every FMA a scratch RMW.
__global__ __launch_bounds__(256) void offset_conv_k(const float* __restrict__ x,
                                                     const float* __restrict__ wpt2,
                                                     const float* __restrict__ bp,
                                                     float* __restrict__ off) {
    __shared__ float red[4][64][19];
    int tid = threadIdx.x;
    int pix = tid & 63;
    int cqu = __builtin_amdgcn_readfirstlane(tid >> 6);  // wave-uniform 0..3
    int bid = blockIdx.x;
    int w0  = (bid & 1) * 64;
    int h   = (bid >> 1) & 127;
    int b   = bid >> 8;
    int wo  = w0 + pix;

#define DECL_(i) float a##i = 0.f;
    REP18(DECL_)
#undef DECL_

    int c0 = cqu * 16;
    for (int ci = 0; ci < 16; ++ci) {
        int c = c0 + ci;
        const float* xb = x + (size_t)(b * C_ + c) * HW_;   // SGPR base
        const float* wr = wpt2 + c * 180;                   // SGPR base -> s_load
#pragma unroll
        for (int t = 0; t < 9; ++t) {
            int y  = h + t / 3 - 1;
            int xw = wo + (t % 3) - 1;
            float xv = (y >= 0 && y < H_ && xw >= 0 && xw < W_) ? xb[y * W_ + xw] : 0.f;
            const float* wrow = wr + t * 20;
#define FMA_(i) a##i = fmaf(xv, wrow[i], a##i);
            REP18(FMA_)
#undef FMA_
        }
    }
#define ST_(i) red[cqu][pix][i] = a##i;
    REP18(ST_)
#undef ST_
    __syncthreads();

    size_t base = ((size_t)(b * H_ + h) * W_ + w0) * 18;
#pragma unroll
    for (int it = 0; it < 5; ++it) {
        int idx = it * 256 + tid;
        if (idx < 64 * 18) {
            int p = idx / 18, j = idx % 18;
            float s = red[0][p][j] + red[1][p][j] + red[2][p][j] + red[3][p][j] + bp[j];
            off[base + idx] = s;
        }
    }
}

// ---------------- K2: deform sampling + bf16x3 MFMA GEMM v6 ----------------
// Block: 64 pix x 64 oc, 256 thr = 4 waves. Grid = B*HW/64 = 1024 -> 3-5
// blocks/CU (32KB LDS). All 9 taps' offsets preloaded to regs; tap loop
// fully unrolled (keeps offs[] statically indexed). Per tap: stage samples
// (bilinear f32 -> bf16 hi/lo, [pix][c] XOR-swizzled) + weights ([oc][c]),
// then 2 K-steps x 4 N-tiles x 3 mfma passes.
__global__ __launch_bounds__(256) void deform_gemm_k(const float* __restrict__ xt,
                                                     const float* __restrict__ off,
                                                     const short* __restrict__ wdh,
                                                     const short* __restrict__ wdl,
                                                     float* __restrict__ out) {
    __shared__ __align__(16) short s_sh[64 * 64];   // samples hi [pix][c] 8KB
    __shared__ __align__(16) short s_sl[64 * 64];   // samples lo        8KB
    __shared__ __align__(16) short s_wh[64 * 64];   // weights hi [oc][c] 8KB
    __shared__ __align__(16) short s_wl[64 * 64];   // weights lo        8KB

    int tid = threadIdx.x;
    int bid = blockIdx.x;              // 1024
    int xcd = bid & 7;                 // XCD slab swizzle (L2 locality)
    int idx = bid >> 3;                // 0..127
    int b   = xcd >> 1;
    int h   = ((xcd & 1) << 6) | (idx >> 1);
    int w0  = (idx & 1) * 64;

    // staging roles: 4 threads per pixel, 16 channels each
    int spix = tid & 63;
    int scg  = tid >> 6;
    // GEMM roles
    int lane = tid & 63;
    int wv   = tid >> 6;               // wave -> oc tile
    int l4   = lane & 15;
    int lq   = lane >> 4;
    int ocA  = wv * 16 + l4;

    f32x4 acc[4];
#pragma unroll
    for (int i = 0; i < 4; ++i) acc[i] = (f32x4){0.f, 0.f, 0.f, 0.f};

    // preload all 9 taps' offsets for this thread's pixel (indep loads)
    const float* ob = off + ((size_t)(b * H_ + h) * W_ + w0 + spix) * 18;
    float2 offs[9];
#pragma unroll
    for (int k = 0; k < 9; ++k) offs[k] = *(const float2*)(ob + 2 * k);

    const float* xb = xt + (size_t)b * HW_ * C_;
    int c0 = scg * 16;

#pragma unroll
    for (int k = 0; k < 9; ++k) {
        // ---- stage weight tap: 4096 bf16 per array, swizzled ----
#pragma unroll
        for (int i = 0; i < 2; ++i) {
            int e    = (i * 256 + tid) * 8;
            int row  = e >> 6;
            int colb = (e & 63) * 2;
            int db   = (row * 128 + colb) ^ ((row & 7) << 4);
            *(bf16x8*)((char*)s_wh + db) = *(const bf16x8*)(wdh + k * 4096 + e);
            *(bf16x8*)((char*)s_wl + db) = *(const bf16x8*)(wdl + k * 4096 + e);
        }
        // ---- stage samples: bilinear 16 c per thread, split hi/lo ----
        {
            float2 o2 = offs[k];
            float py = o2.x + (float)(h - 1 + k / 3);
            float px = o2.y + (float)(w0 + spix - 1 + (k % 3));
            float fy = floorf(py), fx = floorf(px);
            float wy = py - fy, wx = px - fx;
            int y0 = (int)fy, x0 = (int)fx;
            int y1 = y0 + 1,  x1 = x0 + 1;
            float w00 = (1.f - wy) * (1.f - wx);
            float w01 = (1.f - wy) * wx;
            float w10 = wy * (1.f - wx);
            float w11 = wy * wx;
            bool vy0 = (y0 >= 0) & (y0 < H_), vy1 = (y1 >= 0) & (y1 < H_);
            bool vx0 = (x0 >= 0) & (x0 < W_), vx1 = (x1 >= 0) & (x1 < W_);
            w00 *= (float)(vy0 & vx0);
            w01 *= (float)(vy0 & vx1);
            w10 *= (float)(vy1 & vx0);
            w11 *= (float)(vy1 & vx1);
            int cy0 = min(max(y0, 0), H_ - 1), cy1 = min(max(y1, 0), H_ - 1);
            int cx0 = min(max(x0, 0), W_ - 1), cx1 = min(max(x1, 0), W_ - 1);
            const float4* p00 = (const float4*)(xb + ((size_t)cy0 * W_ + cx0) * C_ + c0);
            const float4* p01 = (const float4*)(xb + ((size_t)cy0 * W_ + cx1) * C_ + c0);
            const float4* p10 = (const float4*)(xb + ((size_t)cy1 * W_ + cx0) * C_ + c0);
            const float4* p11 = (const float4*)(xb + ((size_t)cy1 * W_ + cx1) * C_ + c0);
            float sv[16];
#pragma unroll
            for (int i = 0; i < 4; ++i) {
                float4 a = p00[i], bq = p01[i], cq = p10[i], dq = p11[i];
                sv[i * 4 + 0] = w00 * a.x + w01 * bq.x + w10 * cq.x + w11 * dq.x;
                sv[i * 4 + 1] = w00 * a.y + w01 * bq.y + w10 * cq.y + w11 * dq.y;
                sv[i * 4 + 2] = w00 * a.z + w01 * bq.z + w10 * cq.z + w11 * dq.z;
                sv[i * 4 + 3] = w00 * a.w + w01 * bq.w + w10 * cq.w + w11 * dq.w;
            }
#pragma unroll
            for (int i = 0; i < 2; ++i) {
                bf16x8 hv, lv;
#pragma unroll
                for (int j = 0; j < 8; ++j) {
                    float s = sv[i * 8 + j];
                    short hs = f2bf(s);
                    hv[j] = hs;
                    lv[j] = f2bf(s - bf2f(hs));
                }
                int db = (spix * 128 + c0 * 2 + i * 16) ^ ((spix & 7) << 4);
                *(bf16x8*)((char*)s_sh + db) = hv;
                *(bf16x8*)((char*)s_sl + db) = lv;
            }
        }
        __syncthreads();

        // ---- GEMM: 2 K-steps x 4 N-tiles x 3 passes ----
#pragma unroll
        for (int ks = 0; ks < 2; ++ks) {
            int ab = (ocA * 128 + ks * 64 + lq * 16) ^ ((ocA & 7) << 4);
            bf16x8 ah = *(const bf16x8*)((char*)s_wh + ab);
            bf16x8 al = *(const bf16x8*)((char*)s_wl + ab);
#pragma unroll
            for (int nt = 0; nt < 4; ++nt) {
                int prow = nt * 16 + l4;
                int bb = (prow * 128 + ks * 64 + lq * 16) ^ ((prow & 7) << 4);
                bf16x8 bh = *(const bf16x8*)((char*)s_sh + bb);
                bf16x8 bl = *(const bf16x8*)((char*)s_sl + bb);
                acc[nt] = __builtin_amdgcn_mfma_f32_16x16x32_bf16(ah, bh, acc[nt], 0, 0, 0);
                acc[nt] = __builtin_amdgcn_mfma_f32_16x16x32_bf16(ah, bl, acc[nt], 0, 0, 0);
                acc[nt] = __builtin_amdgcn_mfma_f32_16x16x32_bf16(al, bh, acc[nt], 0, 0, 0);
            }
        }
        __syncthreads();
    }

    // ---- epilogue: D col=lane&15 -> pix, row=(lane>>4)*4+r -> oc ----
    int oc0 = wv * 16 + lq * 4;
#pragma unroll
    for (int nt = 0; nt < 4; ++nt) {
#pragma unroll
        for (int r = 0; r < 4; ++r) {
            out[((size_t)(b * CO_ + oc0 + r) * H_ + h) * W_ + w0 + nt * 16 + l4] = acc[nt][r];
        }
    }
}

extern "C" void kernel_launch(void* const* d_in, const int* in_sizes, int n_in,
                              void* d_out, int out_size, void* d_ws, size_t ws_size,
                              hipStream_t stream) {
    const float* x  = (const float*)d_in[0];
    const float* wp = (const float*)d_in[1];
    const float* bp = (const float*)d_in[2];
    const float* wd = (const float*)d_in[3];
    float* out = (float*)d_out;
    float* ws  = (float*)d_ws;

    float* xt   = ws + XT_OFF;
    float* off  = ws + OFF_OFF;
    float* wpt2 = ws + WPT2_OFF;
    short* wdh  = (short*)(ws + WDH_OFF);
    short* wdl  = (short*)(ws + WDL_OFF);

    transpose_x_k<<<B_ * H_ * (W_ / 64), 256, 0, stream>>>(x, xt);
    transpose_w_k<<<(K_ * CO_ * C_ + 255) / 256, 256, 0, stream>>>(wd, wp, wdh, wdl, wpt2);
    offset_conv_k<<<B_ * H_ * 2, 256, 0, stream>>>(x, wpt2, bp, off);
    deform_gemm_k<<<B_ * HW_ / 64, 256, 0, stream>>>(xt, off, wdh, wdl, out);
}